// Round 5
// baseline (412.017 us; speedup 1.0000x reference)
//
#include <hip/hip_runtime.h>
#include <hip/hip_bf16.h>

// Problem constants
#define NN 384            // sequence dim
#define CZ 128            // channels
#define NH 4              // heads
#define HD 32             // head dim
#define MROWS (NN*NN)     // 147456 GEMM rows

typedef __hip_bfloat16 bf16;
typedef short bf16x8f __attribute__((ext_vector_type(8)));          // MFMA A/B operand (8 bf16)
typedef float f32x4 __attribute__((ext_vector_type(4)));            // MFMA C/D operand
typedef unsigned short u16x8 __attribute__((ext_vector_type(8)));   // staging store type
typedef unsigned int uint4v __attribute__((ext_vector_type(4)));

// bf16 <-> f32 helpers (bit-level, RNE)
__device__ __forceinline__ float b2f(unsigned short u) {
    return __uint_as_float(((unsigned)u) << 16);
}
__device__ __forceinline__ unsigned short f2b(float f) {
    unsigned u = __float_as_uint(f);
    return (unsigned short)((u + 0x7FFFu + ((u >> 16) & 1u)) >> 16);
}
// packed 2xbf16 from 2 floats (RNE), single instruction
__device__ __forceinline__ unsigned cvt_pk_bf16(float lo, float hi) {
    unsigned r;
    asm("v_cvt_pk_bf16_f32 %0, %1, %2" : "=v"(r) : "v"(lo), "v"(hi));
    return r;
}
// raw v_exp_f32 = exp2
__device__ __forceinline__ float fexp2(float x) {
    float r;
    asm("v_exp_f32 %0, %1" : "=v"(r) : "v"(x));
    return r;
}

// ---------------------------------------------------------------------------
// qkv GEMM on MFMA (bf16 inputs, f32 accumulate), LayerNorm FULLY fused:
// stats computed in the staging loop (16 threads own one full 128-row; XOR
// chunk swizzle is a bijection on the 16 chunks, so a 4-step 16-lane
// shfl_xor reduce yields sum/sumsq of the whole row).  No ln_stats kernel,
// no mu/rstd traffic.
//   qkv = LN(z) @ qkv_w + qkv_b, scattered as bf16 into qkv_t[t][h][n][i][d].
// Operands SWAPPED: mfma(A = W-cols frag, B = LN(z)-rows frag) so the 4 acc
// regs are 4 CONSECUTIVE out-cols -> single ushort4 store per fragment.
// Tile: 128 z-rows x 64 out-cols, K = 128 staged once.  LDS: 32 KB.
// ---------------------------------------------------------------------------
__global__ __launch_bounds__(256) void qkv_gemm_mfma_kernel(const float* __restrict__ z,
                                                            const float* __restrict__ lnw,
                                                            const float* __restrict__ lnb,
                                                            const float* __restrict__ W,
                                                            const float* __restrict__ bias,
                                                            unsigned short* __restrict__ qkv_t) {
    __shared__ unsigned short Zt[128 * 128];   // 32 KB: slot16 (row, c') holds k-chunk c'^(row&7)

    const int tid = threadIdx.x;
    const int w = tid >> 6;
    const int l = tid & 63;
    const int col0 = blockIdx.x * 64;    // out-col block (x fastest: W panel + z rows L2-hot)
    const int row0 = blockIdx.y * 128;   // z-row block
    const int wcol = w & 1;
    const int wrow = w >> 1;
    const int lm = l & 15;
    const int lq = l >> 4;

    // ---- stage LN(z) tile into swizzled LDS as bf16, stats fused ----
    #pragma unroll
    for (int it = 0; it < 8; it++) {
        const int s = it * 256 + tid;          // 2048 16B slots
        const int r = s >> 4;
        const int c = (s & 15) ^ (r & 7);      // inverse swizzle on source chunk
        const int k0 = c * 8;
        const int grow = row0 + r;
        const float4 z0 = *(const float4*)(z + (size_t)grow * CZ + k0);
        const float4 z1 = *(const float4*)(z + (size_t)grow * CZ + k0 + 4);
        // row stats: 16 lanes (same tid>>4 group) hold the full row
        float sum = z0.x + z0.y + z0.z + z0.w + z1.x + z1.y + z1.z + z1.w;
        float sq  = z0.x*z0.x + z0.y*z0.y + z0.z*z0.z + z0.w*z0.w
                  + z1.x*z1.x + z1.y*z1.y + z1.z*z1.z + z1.w*z1.w;
        #pragma unroll
        for (int o = 1; o < 16; o <<= 1) {
            sum += __shfl_xor(sum, o, 64);
            sq  += __shfl_xor(sq,  o, 64);
        }
        const float mval = sum * (1.0f / CZ);
        const float rs   = rsqrtf(sq * (1.0f / CZ) - mval * mval + 1e-5f);
        const float4 w0 = *(const float4*)(lnw + k0);
        const float4 w1 = *(const float4*)(lnw + k0 + 4);
        const float4 b0 = *(const float4*)(lnb + k0);
        const float4 b1 = *(const float4*)(lnb + k0 + 4);
        u16x8 pk;
        pk[0] = f2b((z0.x - mval) * rs * w0.x + b0.x);
        pk[1] = f2b((z0.y - mval) * rs * w0.y + b0.y);
        pk[2] = f2b((z0.z - mval) * rs * w0.z + b0.z);
        pk[3] = f2b((z0.w - mval) * rs * w0.w + b0.w);
        pk[4] = f2b((z1.x - mval) * rs * w1.x + b1.x);
        pk[5] = f2b((z1.y - mval) * rs * w1.y + b1.y);
        pk[6] = f2b((z1.z - mval) * rs * w1.z + b1.z);
        pk[7] = f2b((z1.w - mval) * rs * w1.w + b1.w);
        *(u16x8*)&Zt[s * 8] = pk;
    }

    // ---- W fragments direct global->reg ----
    bf16x8f a[2][4];
    #pragma unroll
    for (int fm = 0; fm < 2; fm++) {
        const int gcol = col0 + wcol * 32 + fm * 16 + lm;
        #pragma unroll
        for (int kk = 0; kk < 4; kk++) {
            const int kb = kk * 32 + lq * 8;
            #pragma unroll
            for (int j = 0; j < 8; j++)
                a[fm][kk][j] = (short)f2b(W[(size_t)(kb + j) * (3 * CZ) + gcol]);
        }
    }

    __syncthreads();

    // ---- MFMA main: 4 k-steps x (2 col-frags x 4 row-frags) = 32 MFMA/wave
    f32x4 acc[2][4];
    #pragma unroll
    for (int fm = 0; fm < 2; fm++)
        #pragma unroll
        for (int fn = 0; fn < 4; fn++)
            acc[fm][fn] = (f32x4){0.0f, 0.0f, 0.0f, 0.0f};

    #pragma unroll
    for (int kk = 0; kk < 4; kk++) {
        bf16x8f bf[4];
        #pragma unroll
        for (int fn = 0; fn < 4; fn++) {
            const int r = wrow * 64 + fn * 16 + lm;
            const int ch = (kk * 4 + lq) ^ (r & 7);     // swizzled chunk index
            bf[fn] = *(const bf16x8f*)&Zt[(r * 16 + ch) * 8];
        }
        #pragma unroll
        for (int fm = 0; fm < 2; fm++)
            #pragma unroll
            for (int fn = 0; fn < 4; fn++)
                acc[fm][fn] = __builtin_amdgcn_mfma_f32_16x16x32_bf16(a[fm][kk], bf[fn],
                                                                      acc[fm][fn], 0, 0, 0);
    }

    // ---- epilogue: bias + pack + scatter (4 consecutive d per ushort4) ----
    #pragma unroll
    for (int fm = 0; fm < 2; fm++) {
        const int gc = col0 + wcol * 32 + fm * 16 + lq * 4;   // out-col of reg 0
        const float4 b4 = *(const float4*)(bias + gc);
        const int t  = gc >> 7;
        const int hh = (gc & 127) >> 5;
        const int d0 = gc & 31;
        const size_t colbase = (size_t)((t * NH + hh) * NN) * (NN * HD) + d0;
        #pragma unroll
        for (int fn = 0; fn < 4; fn++) {
            const int grow = row0 + wrow * 64 + fn * 16 + lm;  // = i*NN + n
            const int i  = grow / NN;
            const int n0 = grow - i * NN;
            const size_t idx = colbase + (size_t)n0 * (NN * HD) + (size_t)i * HD;
            ushort4 pk;
            pk.x = f2b(acc[fm][fn][0] + b4.x);
            pk.y = f2b(acc[fm][fn][1] + b4.y);
            pk.z = f2b(acc[fm][fn][2] + b4.z);
            pk.w = f2b(acc[fm][fn][3] + b4.w);
            *(ushort4*)(qkv_t + idx) = pk;
        }
    }
}

// ---------------------------------------------------------------------------
// MFMA attention per (n,h), single pass, in-register P transpose, SOFTWARE-
// PIPELINED: one barrier per j-tile (was two).  Double-buffered Vf/sred;
// PV(cl-1) runs in the same barrier-free region as V'(cl) staging and the
// next tile's S/exp VALU -> MFMA/VALU overlap.  Q frags load DIRECT from
// global (fragment layout == global layout, coalesced 1KB/wave) -> Qf LDS
// dropped.  cl-loop fully unrolled so paw[cl&1] double-buffer is static
// (rule #20).  exp via raw v_exp_f32 with scale*log2e folded.
// LDS: Kf 24K + Vf 4K + sred 1K = 29 KB.
// ---------------------------------------------------------------------------
__global__ __launch_bounds__(256) void attn_mfma_kernel(const unsigned short* __restrict__ qkv_t,
                                                        float* __restrict__ attn_out) {
    __shared__ unsigned short Kf[24 * 512];    // frag-order: tile*512 + lane*8
    __shared__ unsigned short Vf[2][1024];     // double-buffered B-frags for j-tile
    __shared__ float sred[2][4][32];           // double-buffered per-wave colsum partials

    const int b = blockIdx.x;
    const int n = b >> 2;
    const int h = b & 3;
    const int tid = threadIdx.x;
    const int w = tid >> 6;        // wave 0..3
    const int l = tid & 63;        // lane
    const int q = l >> 4;          // quad 0..3
    const int m = l & 15;          // low lane bits
    const size_t base_q = (size_t)((0 * NH + h) * NN + n) * (NN * HD);
    const size_t base_k = (size_t)((1 * NH + h) * NN + n) * (NN * HD);
    const size_t base_v = (size_t)((2 * NH + h) * NN + n) * (NN * HD);
    const float SC2 = 0.17677669529663687f * 1.4426950408889634f;  // scale*log2(e)
    const f32x4 zero = {0.0f, 0.0f, 0.0f, 0.0f};

    // ---- Stage K into fragment-order LDS (1536 16B slots) ----
    #pragma unroll
    for (int it = 0; it < 6; it++) {
        const int slot = tid + it * 256;
        const int t  = slot >> 6;
        const int l2 = slot & 63;
        const int row = t * 16 + (l2 & 15);
        const int off8 = (l2 >> 4) * 8;
        *(u16x8*)(Kf + slot * 8) =
            *(const u16x8*)(qkv_t + base_k + (size_t)row * HD + off8);
    }
    // ---- Q fragments DIRECT from global (layout == fragment layout) ----
    bf16x8f qreg[6];
    #pragma unroll
    for (int tt = 0; tt < 6; tt++) {
        const int row = (w + 4 * tt) * 16 + m;
        qreg[tt] = *(const bf16x8f*)(qkv_t + base_q + (size_t)row * HD + q * 8);
    }
    __syncthreads();

    f32x4 oacc[6][2];
    #pragma unroll
    for (int tt = 0; tt < 6; tt++) {
        oacc[tt][0] = zero;
        oacc[tt][1] = zero;
    }

    unsigned pawA[6][4], pawB[6][4];     // double-buffered PV A-frag words
    const int jj  = tid >> 3;            // 0..31 local j (V staging role)
    const int d0v = (tid & 7) * 4;       // 0..28
    const int slotbase = (d0v >> 4) * 64 + (jj >> 3) * 16 + (d0v & 15);
    const int e = jj & 7;

    #pragma unroll
    for (int cl = 0; cl < 12; cl++) {
        const int buf = cl & 1;          // folds: loop fully unrolled
        const bf16x8f ka0 = *(const bf16x8f*)&Kf[(cl * 2 + 0) * 512 + l * 8];
        const bf16x8f ka1 = *(const bf16x8f*)&Kf[(cl * 2 + 1) * 512 + l * 8];
        // prefetch this tile's V rows (hides global latency under S compute)
        const ushort4 v4 = *(const ushort4*)(qkv_t + base_v +
                                             (size_t)(cl * 32 + jj) * HD + d0v);

        float sacc[8];
        #pragma unroll
        for (int k = 0; k < 8; k++) sacc[k] = 0.0f;

        #pragma unroll
        for (int tt = 0; tt < 6; tt++) {
            // S^T tiles: rows j (quad*4+reg), cols i (m); computed ONCE
            const f32x4 sT0 = __builtin_amdgcn_mfma_f32_16x16x32_bf16(ka0, qreg[tt], zero, 0, 0, 0);
            const f32x4 sT1 = __builtin_amdgcn_mfma_f32_16x16x32_bf16(ka1, qreg[tt], zero, 0, 0, 0);
            float p[8];
            p[0] = fexp2(sT0[0] * SC2);
            p[1] = fexp2(sT0[1] * SC2);
            p[2] = fexp2(sT0[2] * SC2);
            p[3] = fexp2(sT0[3] * SC2);
            p[4] = fexp2(sT1[0] * SC2);
            p[5] = fexp2(sT1[1] * SC2);
            p[6] = fexp2(sT1[2] * SC2);
            p[7] = fexp2(sT1[3] * SC2);
            #pragma unroll
            for (int k = 0; k < 8; k++) sacc[k] += p[k];
            // pack: c[2s+u] holds word W = 8s+4h+2g+u (h,g = lane bits 5,4)
            unsigned c0 = cvt_pk_bf16(p[0], p[1]);
            unsigned c1 = cvt_pk_bf16(p[2], p[3]);
            unsigned c2 = cvt_pk_bf16(p[4], p[5]);
            unsigned c3 = cvt_pk_bf16(p[6], p[7]);
            // in-register transpose (h,g,s) -> (s,h,g):
            asm("v_permlane32_swap_b32 %0, %1" : "+v"(c0), "+v"(c2));
            asm("v_permlane32_swap_b32 %0, %1" : "+v"(c1), "+v"(c3));
            asm("v_permlane16_swap_b32 %0, %1" : "+v"(c0), "+v"(c2));
            asm("v_permlane16_swap_b32 %0, %1" : "+v"(c1), "+v"(c3));
            if (buf == 0) {
                pawA[tt][0] = c0; pawA[tt][1] = c1; pawA[tt][2] = c2; pawA[tt][3] = c3;
            } else {
                pawB[tt][0] = c0; pawB[tt][1] = c1; pawB[tt][2] = c2; pawB[tt][3] = c3;
            }
        }

        // ---- column-sum partials: reduce over i-lanes (m), write sred ----
        #pragma unroll
        for (int k = 0; k < 8; k++) {
            float v = sacc[k];
            v += __shfl_xor(v, 1, 64);
            v += __shfl_xor(v, 2, 64);
            v += __shfl_xor(v, 4, 64);
            v += __shfl_xor(v, 8, 64);
            if (m == 0) sred[buf][w][q * 4 + (k & 3) + (k >> 2) * 16] = v;
        }
        __syncthreads();   // the ONLY barrier per j-tile

        // ---- stage V'[j] = V[j]/s_j into Vf[buf] (prefetched v4) ----
        {
            const float inv = 1.0f / (sred[buf][0][jj] + sred[buf][1][jj] +
                                      sred[buf][2][jj] + sred[buf][3][jj]);
            Vf[buf][(slotbase + 0) * 8 + e] = f2b(b2f(v4.x) * inv);
            Vf[buf][(slotbase + 1) * 8 + e] = f2b(b2f(v4.y) * inv);
            Vf[buf][(slotbase + 2) * 8 + e] = f2b(b2f(v4.z) * inv);
            Vf[buf][(slotbase + 3) * 8 + e] = f2b(b2f(v4.w) * inv);
        }

        // ---- PV(cl-1) from Vf[buf^1] + paw(prev): overlaps staging and the
        //      next tile's S/exp VALU (no barrier in between) ----
        if (cl > 0) {
            const bf16x8f vb0 = *(const bf16x8f*)&Vf[buf ^ 1][(0 * 64 + l) * 8];
            const bf16x8f vb1 = *(const bf16x8f*)&Vf[buf ^ 1][(1 * 64 + l) * 8];
            #pragma unroll
            for (int tt = 0; tt < 6; tt++) {
                uint4v u;
                if (buf == 1) { u = (uint4v){pawA[tt][0], pawA[tt][1], pawA[tt][2], pawA[tt][3]}; }
                else          { u = (uint4v){pawB[tt][0], pawB[tt][1], pawB[tt][2], pawB[tt][3]}; }
                const bf16x8f pa = __builtin_bit_cast(bf16x8f, u);
                oacc[tt][0] = __builtin_amdgcn_mfma_f32_16x16x32_bf16(pa, vb0, oacc[tt][0], 0, 0, 0);
                oacc[tt][1] = __builtin_amdgcn_mfma_f32_16x16x32_bf16(pa, vb1, oacc[tt][1], 0, 0, 0);
            }
        }
    }

    // ---- drain: PV(11) from Vf[1] + pawB ----
    __syncthreads();
    {
        const bf16x8f vb0 = *(const bf16x8f*)&Vf[1][(0 * 64 + l) * 8];
        const bf16x8f vb1 = *(const bf16x8f*)&Vf[1][(1 * 64 + l) * 8];
        #pragma unroll
        for (int tt = 0; tt < 6; tt++) {
            const uint4v u = {pawB[tt][0], pawB[tt][1], pawB[tt][2], pawB[tt][3]};
            const bf16x8f pa = __builtin_bit_cast(bf16x8f, u);
            oacc[tt][0] = __builtin_amdgcn_mfma_f32_16x16x32_bf16(pa, vb0, oacc[tt][0], 0, 0, 0);
            oacc[tt][1] = __builtin_amdgcn_mfma_f32_16x16x32_bf16(pa, vb1, oacc[tt][1], 0, 0, 0);
        }
    }

    // ---- Store O: rows i = it*16 + q*4 + r, col d = dt*16 + m ----
    #pragma unroll
    for (int tt = 0; tt < 6; tt++) {
        const int it = w + 4 * tt;
        #pragma unroll
        for (int dt = 0; dt < 2; dt++) {
            #pragma unroll
            for (int r = 0; r < 4; r++) {
                const int i = it * 16 + q * 4 + r;
                attn_out[((size_t)i * NN + n) * CZ + h * HD + dt * 16 + m] = oacc[tt][dt][r];
            }
        }
    }
}

// ---------------------------------------------------------------------------
// Final dual GEMM on MFMA (bf16 inputs, f32 accumulate), in place on out:
//   out = z + sigmoid(LN(z)@gate_w+gate_b) * (attn@out_w + out_b)
// LayerNorm stats fused into staging (same 16-lane reduce as qkv kernel).
// Tile: 64 rows x 128 cols (full N), K = 128 in one shot; 4 waves each own a
// 32-col slice.  Both row operands staged as bf16 into XOR-swizzled LDS.
// ---------------------------------------------------------------------------
__global__ __launch_bounds__(256) void final_mfma_kernel(const float* __restrict__ z,
                                                         const float* __restrict__ lnw,
                                                         const float* __restrict__ lnb,
                                                         const float* __restrict__ gate_w,
                                                         const float* __restrict__ gate_b,
                                                         const float* __restrict__ out_w,
                                                         const float* __restrict__ out_b,
                                                         float* out) {
    __shared__ unsigned short Zt[64 * 128];   // LN(z) bf16, swizzled (16 KB)
    __shared__ unsigned short At[64 * 128];   // attn  bf16, swizzled (16 KB)

    const int tid = threadIdx.x;
    const int w = tid >> 6;        // wave = col slice 0..3 (32 cols each)
    const int l = tid & 63;
    const int lm = l & 15;
    const int lq = l >> 4;
    const int row0 = blockIdx.x * 64;

    // ---- stage LN(z) and attn tiles into swizzled LDS as bf16 ----
    #pragma unroll
    for (int it = 0; it < 4; it++) {
        const int s = it * 256 + tid;          // 1024 16B slots
        const int r = s >> 4;                  // 0..63
        const int c = (s & 15) ^ (r & 7);      // inverse swizzle on source chunk
        const int k0 = c * 8;
        const int grow = row0 + r;
        const size_t gi = (size_t)grow * CZ + k0;
        const float4 z0 = *(const float4*)(z + gi);
        const float4 z1 = *(const float4*)(z + gi + 4);
        const float4 a0 = *(const float4*)(out + gi);
        const float4 a1 = *(const float4*)(out + gi + 4);
        // row stats over the 16-lane group (full row covered via XOR bijection)
        float sum = z0.x + z0.y + z0.z + z0.w + z1.x + z1.y + z1.z + z1.w;
        float sq  = z0.x*z0.x + z0.y*z0.y + z0.z*z0.z + z0.w*z0.w
                  + z1.x*z1.x + z1.y*z1.y + z1.z*z1.z + z1.w*z1.w;
        #pragma unroll
        for (int o = 1; o < 16; o <<= 1) {
            sum += __shfl_xor(sum, o, 64);
            sq  += __shfl_xor(sq,  o, 64);
        }
        const float mval = sum * (1.0f / CZ);
        const float rs   = rsqrtf(sq * (1.0f / CZ) - mval * mval + 1e-5f);
        const float4 w0 = *(const float4*)(lnw + k0);
        const float4 w1 = *(const float4*)(lnw + k0 + 4);
        const float4 b0 = *(const float4*)(lnb + k0);
        const float4 b1 = *(const float4*)(lnb + k0 + 4);
        u16x8 pz, pa;
        pz[0] = f2b((z0.x - mval) * rs * w0.x + b0.x);
        pz[1] = f2b((z0.y - mval) * rs * w0.y + b0.y);
        pz[2] = f2b((z0.z - mval) * rs * w0.z + b0.z);
        pz[3] = f2b((z0.w - mval) * rs * w0.w + b0.w);
        pz[4] = f2b((z1.x - mval) * rs * w1.x + b1.x);
        pz[5] = f2b((z1.y - mval) * rs * w1.y + b1.y);
        pz[6] = f2b((z1.z - mval) * rs * w1.z + b1.z);
        pz[7] = f2b((z1.w - mval) * rs * w1.w + b1.w);
        pa[0] = f2b(a0.x); pa[1] = f2b(a0.y); pa[2] = f2b(a0.z); pa[3] = f2b(a0.w);
        pa[4] = f2b(a1.x); pa[5] = f2b(a1.y); pa[6] = f2b(a1.z); pa[7] = f2b(a1.w);
        *(u16x8*)&Zt[s * 8] = pz;
        *(u16x8*)&At[s * 8] = pa;
    }

    // ---- W fragments direct global->reg (gate_w and out_w, 32-col slice) ----
    bf16x8f gw[2][4], ow[2][4];
    #pragma unroll
    for (int fm = 0; fm < 2; fm++) {
        const int gcol = w * 32 + fm * 16 + lm;
        #pragma unroll
        for (int kk = 0; kk < 4; kk++) {
            const int kb = kk * 32 + lq * 8;
            #pragma unroll
            for (int j = 0; j < 8; j++) {
                gw[fm][kk][j] = (short)f2b(gate_w[(size_t)(kb + j) * CZ + gcol]);
                ow[fm][kk][j] = (short)f2b(out_w [(size_t)(kb + j) * CZ + gcol]);
            }
        }
    }

    __syncthreads();

    // ---- MFMA main: 4 k-steps x 2 col-frags x 4 row-frags x 2 GEMMs ----
    f32x4 acc1[2][4], acc2[2][4];
    #pragma unroll
    for (int fm = 0; fm < 2; fm++)
        #pragma unroll
        for (int fn = 0; fn < 4; fn++) {
            acc1[fm][fn] = (f32x4){0.0f, 0.0f, 0.0f, 0.0f};
            acc2[fm][fn] = (f32x4){0.0f, 0.0f, 0.0f, 0.0f};
        }

    #pragma unroll
    for (int kk = 0; kk < 4; kk++) {
        bf16x8f bz[4], ba[4];
        #pragma unroll
        for (int fn = 0; fn < 4; fn++) {
            const int r = fn * 16 + lm;
            const int ch = (kk * 4 + lq) ^ (r & 7);     // swizzled chunk index
            bz[fn] = *(const bf16x8f*)&Zt[(r * 16 + ch) * 8];
            ba[fn] = *(const bf16x8f*)&At[(r * 16 + ch) * 8];
        }
        #pragma unroll
        for (int fm = 0; fm < 2; fm++)
            #pragma unroll
            for (int fn = 0; fn < 4; fn++) {
                acc1[fm][fn] = __builtin_amdgcn_mfma_f32_16x16x32_bf16(gw[fm][kk], bz[fn],
                                                                       acc1[fm][fn], 0, 0, 0);
                acc2[fm][fn] = __builtin_amdgcn_mfma_f32_16x16x32_bf16(ow[fm][kk], ba[fn],
                                                                       acc2[fm][fn], 0, 0, 0);
            }
    }

    // ---- epilogue: sigmoid-gate + residual, float4 in-place store ----
    #pragma unroll
    for (int fm = 0; fm < 2; fm++) {
        const int gc = w * 32 + fm * 16 + lq * 4;       // out-col of reg 0
        const float4 gb4 = *(const float4*)(gate_b + gc);
        const float4 ob4 = *(const float4*)(out_b + gc);
        #pragma unroll
        for (int fn = 0; fn < 4; fn++) {
            const int grow = row0 + fn * 16 + lm;
            const size_t idx = (size_t)grow * CZ + gc;
            const float4 z4 = *(const float4*)(z + idx);
            float4 o;
            o.x = z4.x + (1.0f / (1.0f + __expf(-(acc1[fm][fn][0] + gb4.x)))) * (acc2[fm][fn][0] + ob4.x);
            o.y = z4.y + (1.0f / (1.0f + __expf(-(acc1[fm][fn][1] + gb4.y)))) * (acc2[fm][fn][1] + ob4.y);
            o.z = z4.z + (1.0f / (1.0f + __expf(-(acc1[fm][fn][2] + gb4.z)))) * (acc2[fm][fn][2] + ob4.z);
            o.w = z4.w + (1.0f / (1.0f + __expf(-(acc1[fm][fn][3] + gb4.w)))) * (acc2[fm][fn][3] + ob4.w);
            *(float4*)(out + idx) = o;
        }
    }
}

// ---------------------------------------------------------------------------
extern "C" void kernel_launch(void* const* d_in, const int* in_sizes, int n_in,
                              void* d_out, int out_size, void* d_ws, size_t ws_size,
                              hipStream_t stream) {
    const float* z      = (const float*)d_in[0];
    const float* ln_w   = (const float*)d_in[1];
    const float* ln_b   = (const float*)d_in[2];
    const float* qkv_w  = (const float*)d_in[3];
    const float* qkv_b  = (const float*)d_in[4];
    const float* out_w  = (const float*)d_in[5];
    const float* out_b  = (const float*)d_in[6];
    const float* gate_w = (const float*)d_in[7];
    const float* gate_b = (const float*)d_in[8];
    float* out = (float*)d_out;

    // Workspace: qkv_t (bf16) ~= 113 MiB
    unsigned short* qkv_t = (unsigned short*)d_ws;

    qkv_gemm_mfma_kernel<<<dim3(6, MROWS / 128), 256, 0, stream>>>(z, ln_w, ln_b,
                                                                   qkv_w, qkv_b, qkv_t);
    attn_mfma_kernel<<<NN * NH, 256, 0, stream>>>(qkv_t, out);
    final_mfma_kernel<<<MROWS / 64, 256, 0, stream>>>(z, ln_w, ln_b,
                                                      gate_w, gate_b, out_w, out_b, out);
}

// Round 6
// 391.189 us; speedup vs baseline: 1.0532x; 1.0532x over previous
//
#include <hip/hip_runtime.h>
#include <hip/hip_bf16.h>

// Problem constants
#define NN 384            // sequence dim
#define CZ 128            // channels
#define NH 4              // heads
#define HD 32             // head dim
#define MROWS (NN*NN)     // 147456 GEMM rows

typedef __hip_bfloat16 bf16;
typedef short bf16x8f __attribute__((ext_vector_type(8)));          // MFMA A/B operand (8 bf16)
typedef float f32x4 __attribute__((ext_vector_type(4)));            // MFMA C/D operand
typedef unsigned short u16x8 __attribute__((ext_vector_type(8)));   // staging store type
typedef unsigned int uint4v __attribute__((ext_vector_type(4)));

// bf16 <-> f32 helpers (bit-level, RNE)
__device__ __forceinline__ float b2f(unsigned short u) {
    return __uint_as_float(((unsigned)u) << 16);
}
__device__ __forceinline__ unsigned short f2b(float f) {
    unsigned u = __float_as_uint(f);
    return (unsigned short)((u + 0x7FFFu + ((u >> 16) & 1u)) >> 16);
}
// packed 2xbf16 from 2 floats (RNE), single instruction
__device__ __forceinline__ unsigned cvt_pk_bf16(float lo, float hi) {
    unsigned r;
    asm("v_cvt_pk_bf16_f32 %0, %1, %2" : "=v"(r) : "v"(lo), "v"(hi));
    return r;
}
// raw v_exp_f32 = exp2
__device__ __forceinline__ float fexp2(float x) {
    float r;
    asm("v_exp_f32 %0, %1" : "=v"(r) : "v"(x));
    return r;
}

// ---------------------------------------------------------------------------
// LayerNorm stats: one wave per row of 128; writes mu[r], rstd[r].
// (Fusing these into the GEMM staging loops was tried in round 4 and
//  REGRESSED ~75 µs total: the 4-deep shfl_xor chain + rsqrt on the staging
//  critical path serializes through the in-order DS pipe. Keep separate.)
// ---------------------------------------------------------------------------
__global__ __launch_bounds__(256) void ln_stats_kernel(const float* __restrict__ z,
                                                       float* __restrict__ mu,
                                                       float* __restrict__ rstd) {
    const int wave = threadIdx.x >> 6;
    const int lane = threadIdx.x & 63;
    const int r = blockIdx.x * 4 + wave;
    const float* zr = z + (size_t)r * CZ;
    float x0 = zr[lane], x1 = zr[lane + 64];
    float sum = x0 + x1;
    float sq  = x0 * x0 + x1 * x1;
    #pragma unroll
    for (int o = 32; o > 0; o >>= 1) {
        sum += __shfl_xor(sum, o, 64);
        sq  += __shfl_xor(sq,  o, 64);
    }
    if (lane == 0) {
        const float m   = sum * (1.0f / CZ);
        const float var = sq * (1.0f / CZ) - m * m;
        mu[r]   = m;
        rstd[r] = rsqrtf(var + 1e-5f);
    }
}

// ---------------------------------------------------------------------------
// qkv GEMM on MFMA (bf16 inputs, f32 accumulate), fused LayerNorm apply:
//   qkv = LN(z) @ qkv_w + qkv_b, scattered as bf16 into qkv_t[t][h][n][i][d].
// Operands SWAPPED: mfma(A = W-cols frag, B = LN(z)-rows frag) so the 4 acc
// regs are 4 CONSECUTIVE out-cols -> single ushort4 store per fragment.
// Tile: 128 z-rows x 64 out-cols, K = 128 staged once.  LN(z) tile -> LDS
// bf16, XOR-swizzled (chunk' = chunk ^ (row&7)).  W frags direct global->reg.
// XCD-CHUNKED grid (1D): xcd = bid&7 owns 144 consecutive row-panels, col
// fastest within -> the 6 col-blocks sharing a z row-panel run consecutively
// on the SAME XCD L2 (round-robin dispatch maps bid%8 -> XCD).  Fixes the
// measured 3x z over-fetch (FETCH 222 MB -> ~90 MB expected).
// LDS: 32 KB.
// ---------------------------------------------------------------------------
__global__ __launch_bounds__(256) void qkv_gemm_mfma_kernel(const float* __restrict__ z,
                                                            const float* __restrict__ mu,
                                                            const float* __restrict__ rstd,
                                                            const float* __restrict__ lnw,
                                                            const float* __restrict__ lnb,
                                                            const float* __restrict__ W,
                                                            const float* __restrict__ bias,
                                                            unsigned short* __restrict__ qkv_t) {
    __shared__ unsigned short Zt[128 * 128];   // 32 KB: slot16 (row, c') holds k-chunk c'^(row&7)

    const int tid = threadIdx.x;
    const int w = tid >> 6;
    const int l = tid & 63;
    // XCD-chunked decomposition: 6912 = 8 XCDs x 144 row-panels x 6 col-blocks
    const int bid = blockIdx.x;
    const int xcd = bid & 7;
    const int idx = bid >> 3;            // 0..863
    const int yt  = idx / 6;             // 0..143
    const int x   = idx - yt * 6;        // 0..5
    const int col0 = x * 64;
    const int row0 = (xcd * 144 + yt) * 128;
    const int wcol = w & 1;
    const int wrow = w >> 1;
    const int lm = l & 15;
    const int lq = l >> 4;

    // ---- stage LN(z) tile into swizzled LDS as bf16 ----
    #pragma unroll
    for (int it = 0; it < 8; it++) {
        const int s = it * 256 + tid;          // 2048 16B slots
        const int r = s >> 4;
        const int c = (s & 15) ^ (r & 7);      // inverse swizzle on source chunk
        const int k0 = c * 8;
        const int grow = row0 + r;
        const float m  = mu[grow];
        const float rs = rstd[grow];
        const float4 z0 = *(const float4*)(z + (size_t)grow * CZ + k0);
        const float4 z1 = *(const float4*)(z + (size_t)grow * CZ + k0 + 4);
        const float4 w0 = *(const float4*)(lnw + k0);
        const float4 w1 = *(const float4*)(lnw + k0 + 4);
        const float4 b0 = *(const float4*)(lnb + k0);
        const float4 b1 = *(const float4*)(lnb + k0 + 4);
        u16x8 pk;
        pk[0] = f2b((z0.x - m) * rs * w0.x + b0.x);
        pk[1] = f2b((z0.y - m) * rs * w0.y + b0.y);
        pk[2] = f2b((z0.z - m) * rs * w0.z + b0.z);
        pk[3] = f2b((z0.w - m) * rs * w0.w + b0.w);
        pk[4] = f2b((z1.x - m) * rs * w1.x + b1.x);
        pk[5] = f2b((z1.y - m) * rs * w1.y + b1.y);
        pk[6] = f2b((z1.z - m) * rs * w1.z + b1.z);
        pk[7] = f2b((z1.w - m) * rs * w1.w + b1.w);
        *(u16x8*)&Zt[s * 8] = pk;
    }

    // ---- W fragments direct global->reg ----
    bf16x8f a[2][4];
    #pragma unroll
    for (int fm = 0; fm < 2; fm++) {
        const int gcol = col0 + wcol * 32 + fm * 16 + lm;
        #pragma unroll
        for (int kk = 0; kk < 4; kk++) {
            const int kb = kk * 32 + lq * 8;
            #pragma unroll
            for (int j = 0; j < 8; j++)
                a[fm][kk][j] = (short)f2b(W[(size_t)(kb + j) * (3 * CZ) + gcol]);
        }
    }

    __syncthreads();

    // ---- MFMA main: 4 k-steps x (2 col-frags x 4 row-frags) = 32 MFMA/wave
    f32x4 acc[2][4];
    #pragma unroll
    for (int fm = 0; fm < 2; fm++)
        #pragma unroll
        for (int fn = 0; fn < 4; fn++)
            acc[fm][fn] = (f32x4){0.0f, 0.0f, 0.0f, 0.0f};

    #pragma unroll
    for (int kk = 0; kk < 4; kk++) {
        bf16x8f bf[4];
        #pragma unroll
        for (int fn = 0; fn < 4; fn++) {
            const int r = wrow * 64 + fn * 16 + lm;
            const int ch = (kk * 4 + lq) ^ (r & 7);     // swizzled chunk index
            bf[fn] = *(const bf16x8f*)&Zt[(r * 16 + ch) * 8];
        }
        #pragma unroll
        for (int fm = 0; fm < 2; fm++)
            #pragma unroll
            for (int fn = 0; fn < 4; fn++)
                acc[fm][fn] = __builtin_amdgcn_mfma_f32_16x16x32_bf16(a[fm][kk], bf[fn],
                                                                      acc[fm][fn], 0, 0, 0);
    }

    // ---- epilogue: bias + pack + scatter (4 consecutive d per ushort4) ----
    #pragma unroll
    for (int fm = 0; fm < 2; fm++) {
        const int gc = col0 + wcol * 32 + fm * 16 + lq * 4;   // out-col of reg 0
        const float4 b4 = *(const float4*)(bias + gc);
        const int t  = gc >> 7;
        const int hh = (gc & 127) >> 5;
        const int d0 = gc & 31;
        const size_t colbase = (size_t)((t * NH + hh) * NN) * (NN * HD) + d0;
        #pragma unroll
        for (int fn = 0; fn < 4; fn++) {
            const int grow = row0 + wrow * 64 + fn * 16 + lm;  // = i*NN + n
            const int i  = grow / NN;
            const int n0 = grow - i * NN;
            const size_t idx2 = colbase + (size_t)n0 * (NN * HD) + (size_t)i * HD;
            ushort4 pk;
            pk.x = f2b(acc[fm][fn][0] + b4.x);
            pk.y = f2b(acc[fm][fn][1] + b4.y);
            pk.z = f2b(acc[fm][fn][2] + b4.z);
            pk.w = f2b(acc[fm][fn][3] + b4.w);
            *(ushort4*)(qkv_t + idx2) = pk;
        }
    }
}

// ---------------------------------------------------------------------------
// MFMA attention per (n,h), single pass, in-register P transpose, SOFTWARE-
// PIPELINED: one barrier per j-tile.  Double-buffered Vf/sred; PV(cl-1) runs
// in the same barrier-free region as V'(cl) staging and the next tile's
// S/exp VALU.  Q frags direct from global; cl-loop fully unrolled (static
// paw double-buffer).  exp via raw v_exp_f32 with scale*log2e folded.
// LDS: Kf 24K + Vf 4K + sred 1K = 29 KB.
// ---------------------------------------------------------------------------
__global__ __launch_bounds__(256) void attn_mfma_kernel(const unsigned short* __restrict__ qkv_t,
                                                        float* __restrict__ attn_out) {
    __shared__ unsigned short Kf[24 * 512];    // frag-order: tile*512 + lane*8
    __shared__ unsigned short Vf[2][1024];     // double-buffered B-frags for j-tile
    __shared__ float sred[2][4][32];           // double-buffered per-wave colsum partials

    const int b = blockIdx.x;
    const int n = b >> 2;
    const int h = b & 3;
    const int tid = threadIdx.x;
    const int w = tid >> 6;        // wave 0..3
    const int l = tid & 63;        // lane
    const int q = l >> 4;          // quad 0..3
    const int m = l & 15;          // low lane bits
    const size_t base_q = (size_t)((0 * NH + h) * NN + n) * (NN * HD);
    const size_t base_k = (size_t)((1 * NH + h) * NN + n) * (NN * HD);
    const size_t base_v = (size_t)((2 * NH + h) * NN + n) * (NN * HD);
    const float SC2 = 0.17677669529663687f * 1.4426950408889634f;  // scale*log2(e)
    const f32x4 zero = {0.0f, 0.0f, 0.0f, 0.0f};

    // ---- Stage K into fragment-order LDS (1536 16B slots) ----
    #pragma unroll
    for (int it = 0; it < 6; it++) {
        const int slot = tid + it * 256;
        const int t  = slot >> 6;
        const int l2 = slot & 63;
        const int row = t * 16 + (l2 & 15);
        const int off8 = (l2 >> 4) * 8;
        *(u16x8*)(Kf + slot * 8) =
            *(const u16x8*)(qkv_t + base_k + (size_t)row * HD + off8);
    }
    // ---- Q fragments DIRECT from global (layout == fragment layout) ----
    bf16x8f qreg[6];
    #pragma unroll
    for (int tt = 0; tt < 6; tt++) {
        const int row = (w + 4 * tt) * 16 + m;
        qreg[tt] = *(const bf16x8f*)(qkv_t + base_q + (size_t)row * HD + q * 8);
    }
    __syncthreads();

    f32x4 oacc[6][2];
    #pragma unroll
    for (int tt = 0; tt < 6; tt++) {
        oacc[tt][0] = zero;
        oacc[tt][1] = zero;
    }

    unsigned pawA[6][4], pawB[6][4];     // double-buffered PV A-frag words
    const int jj  = tid >> 3;            // 0..31 local j (V staging role)
    const int d0v = (tid & 7) * 4;       // 0..28
    const int slotbase = (d0v >> 4) * 64 + (jj >> 3) * 16 + (d0v & 15);
    const int e = jj & 7;

    #pragma unroll
    for (int cl = 0; cl < 12; cl++) {
        const int buf = cl & 1;          // folds: loop fully unrolled
        const bf16x8f ka0 = *(const bf16x8f*)&Kf[(cl * 2 + 0) * 512 + l * 8];
        const bf16x8f ka1 = *(const bf16x8f*)&Kf[(cl * 2 + 1) * 512 + l * 8];
        // prefetch this tile's V rows (hides global latency under S compute)
        const ushort4 v4 = *(const ushort4*)(qkv_t + base_v +
                                             (size_t)(cl * 32 + jj) * HD + d0v);

        float sacc[8];
        #pragma unroll
        for (int k = 0; k < 8; k++) sacc[k] = 0.0f;

        #pragma unroll
        for (int tt = 0; tt < 6; tt++) {
            // S^T tiles: rows j (quad*4+reg), cols i (m); computed ONCE
            const f32x4 sT0 = __builtin_amdgcn_mfma_f32_16x16x32_bf16(ka0, qreg[tt], zero, 0, 0, 0);
            const f32x4 sT1 = __builtin_amdgcn_mfma_f32_16x16x32_bf16(ka1, qreg[tt], zero, 0, 0, 0);
            float p[8];
            p[0] = fexp2(sT0[0] * SC2);
            p[1] = fexp2(sT0[1] * SC2);
            p[2] = fexp2(sT0[2] * SC2);
            p[3] = fexp2(sT0[3] * SC2);
            p[4] = fexp2(sT1[0] * SC2);
            p[5] = fexp2(sT1[1] * SC2);
            p[6] = fexp2(sT1[2] * SC2);
            p[7] = fexp2(sT1[3] * SC2);
            #pragma unroll
            for (int k = 0; k < 8; k++) sacc[k] += p[k];
            // pack: c[2s+u] holds word W = 8s+4h+2g+u (h,g = lane bits 5,4)
            unsigned c0 = cvt_pk_bf16(p[0], p[1]);
            unsigned c1 = cvt_pk_bf16(p[2], p[3]);
            unsigned c2 = cvt_pk_bf16(p[4], p[5]);
            unsigned c3 = cvt_pk_bf16(p[6], p[7]);
            // in-register transpose (h,g,s) -> (s,h,g):
            asm("v_permlane32_swap_b32 %0, %1" : "+v"(c0), "+v"(c2));
            asm("v_permlane32_swap_b32 %0, %1" : "+v"(c1), "+v"(c3));
            asm("v_permlane16_swap_b32 %0, %1" : "+v"(c0), "+v"(c2));
            asm("v_permlane16_swap_b32 %0, %1" : "+v"(c1), "+v"(c3));
            if (buf == 0) {
                pawA[tt][0] = c0; pawA[tt][1] = c1; pawA[tt][2] = c2; pawA[tt][3] = c3;
            } else {
                pawB[tt][0] = c0; pawB[tt][1] = c1; pawB[tt][2] = c2; pawB[tt][3] = c3;
            }
        }

        // ---- column-sum partials: reduce over i-lanes (m), write sred ----
        #pragma unroll
        for (int k = 0; k < 8; k++) {
            float v = sacc[k];
            v += __shfl_xor(v, 1, 64);
            v += __shfl_xor(v, 2, 64);
            v += __shfl_xor(v, 4, 64);
            v += __shfl_xor(v, 8, 64);
            if (m == 0) sred[buf][w][q * 4 + (k & 3) + (k >> 2) * 16] = v;
        }
        __syncthreads();   // the ONLY barrier per j-tile

        // ---- stage V'[j] = V[j]/s_j into Vf[buf] (prefetched v4) ----
        {
            const float inv = 1.0f / (sred[buf][0][jj] + sred[buf][1][jj] +
                                      sred[buf][2][jj] + sred[buf][3][jj]);
            Vf[buf][(slotbase + 0) * 8 + e] = f2b(b2f(v4.x) * inv);
            Vf[buf][(slotbase + 1) * 8 + e] = f2b(b2f(v4.y) * inv);
            Vf[buf][(slotbase + 2) * 8 + e] = f2b(b2f(v4.z) * inv);
            Vf[buf][(slotbase + 3) * 8 + e] = f2b(b2f(v4.w) * inv);
        }

        // ---- PV(cl-1) from Vf[buf^1] + paw(prev): overlaps staging and the
        //      next tile's S/exp VALU (no barrier in between) ----
        if (cl > 0) {
            const bf16x8f vb0 = *(const bf16x8f*)&Vf[buf ^ 1][(0 * 64 + l) * 8];
            const bf16x8f vb1 = *(const bf16x8f*)&Vf[buf ^ 1][(1 * 64 + l) * 8];
            #pragma unroll
            for (int tt = 0; tt < 6; tt++) {
                uint4v u;
                if (buf == 1) { u = (uint4v){pawA[tt][0], pawA[tt][1], pawA[tt][2], pawA[tt][3]}; }
                else          { u = (uint4v){pawB[tt][0], pawB[tt][1], pawB[tt][2], pawB[tt][3]}; }
                const bf16x8f pa = __builtin_bit_cast(bf16x8f, u);
                oacc[tt][0] = __builtin_amdgcn_mfma_f32_16x16x32_bf16(pa, vb0, oacc[tt][0], 0, 0, 0);
                oacc[tt][1] = __builtin_amdgcn_mfma_f32_16x16x32_bf16(pa, vb1, oacc[tt][1], 0, 0, 0);
            }
        }
    }

    // ---- drain: PV(11) from Vf[1] + pawB ----
    __syncthreads();
    {
        const bf16x8f vb0 = *(const bf16x8f*)&Vf[1][(0 * 64 + l) * 8];
        const bf16x8f vb1 = *(const bf16x8f*)&Vf[1][(1 * 64 + l) * 8];
        #pragma unroll
        for (int tt = 0; tt < 6; tt++) {
            const uint4v u = {pawB[tt][0], pawB[tt][1], pawB[tt][2], pawB[tt][3]};
            const bf16x8f pa = __builtin_bit_cast(bf16x8f, u);
            oacc[tt][0] = __builtin_amdgcn_mfma_f32_16x16x32_bf16(pa, vb0, oacc[tt][0], 0, 0, 0);
            oacc[tt][1] = __builtin_amdgcn_mfma_f32_16x16x32_bf16(pa, vb1, oacc[tt][1], 0, 0, 0);
        }
    }

    // ---- Store O: rows i = it*16 + q*4 + r, col d = dt*16 + m ----
    #pragma unroll
    for (int tt = 0; tt < 6; tt++) {
        const int it = w + 4 * tt;
        #pragma unroll
        for (int dt = 0; dt < 2; dt++) {
            #pragma unroll
            for (int r = 0; r < 4; r++) {
                const int i = it * 16 + q * 4 + r;
                attn_out[((size_t)i * NN + n) * CZ + h * HD + dt * 16 + m] = oacc[tt][dt][r];
            }
        }
    }
}

// ---------------------------------------------------------------------------
// Final dual GEMM on MFMA (bf16 inputs, f32 accumulate), in place on out:
//   out = z + sigmoid(LN(z)@gate_w+gate_b) * (attn@out_w + out_b)
// Tile: 64 rows x 128 cols (full N), K = 128 in one shot; 4 waves each own a
// 32-col slice.  Both row operands staged as bf16 into XOR-swizzled LDS.
// LN from precomputed mu/rstd (fusion regressed — see ln_stats note).
// ---------------------------------------------------------------------------
__global__ __launch_bounds__(256) void final_mfma_kernel(const float* __restrict__ z,
                                                         const float* __restrict__ mu,
                                                         const float* __restrict__ rstd,
                                                         const float* __restrict__ lnw,
                                                         const float* __restrict__ lnb,
                                                         const float* __restrict__ gate_w,
                                                         const float* __restrict__ gate_b,
                                                         const float* __restrict__ out_w,
                                                         const float* __restrict__ out_b,
                                                         float* out) {
    __shared__ unsigned short Zt[64 * 128];   // LN(z) bf16, swizzled (16 KB)
    __shared__ unsigned short At[64 * 128];   // attn  bf16, swizzled (16 KB)

    const int tid = threadIdx.x;
    const int w = tid >> 6;        // wave = col slice 0..3 (32 cols each)
    const int l = tid & 63;
    const int lm = l & 15;
    const int lq = l >> 4;
    const int row0 = blockIdx.x * 64;

    // ---- stage LN(z) and attn tiles into swizzled LDS as bf16 ----
    #pragma unroll
    for (int it = 0; it < 4; it++) {
        const int s = it * 256 + tid;          // 1024 16B slots
        const int r = s >> 4;                  // 0..63
        const int c = (s & 15) ^ (r & 7);      // inverse swizzle on source chunk
        const int k0 = c * 8;
        const int grow = row0 + r;
        const float m  = mu[grow];
        const float rs = rstd[grow];
        const size_t gi = (size_t)grow * CZ + k0;
        const float4 z0 = *(const float4*)(z + gi);
        const float4 z1 = *(const float4*)(z + gi + 4);
        const float4 a0 = *(const float4*)(out + gi);
        const float4 a1 = *(const float4*)(out + gi + 4);
        const float4 w0 = *(const float4*)(lnw + k0);
        const float4 w1 = *(const float4*)(lnw + k0 + 4);
        const float4 b0 = *(const float4*)(lnb + k0);
        const float4 b1 = *(const float4*)(lnb + k0 + 4);
        u16x8 pz, pa;
        pz[0] = f2b((z0.x - m) * rs * w0.x + b0.x);
        pz[1] = f2b((z0.y - m) * rs * w0.y + b0.y);
        pz[2] = f2b((z0.z - m) * rs * w0.z + b0.z);
        pz[3] = f2b((z0.w - m) * rs * w0.w + b0.w);
        pz[4] = f2b((z1.x - m) * rs * w1.x + b1.x);
        pz[5] = f2b((z1.y - m) * rs * w1.y + b1.y);
        pz[6] = f2b((z1.z - m) * rs * w1.z + b1.z);
        pz[7] = f2b((z1.w - m) * rs * w1.w + b1.w);
        pa[0] = f2b(a0.x); pa[1] = f2b(a0.y); pa[2] = f2b(a0.z); pa[3] = f2b(a0.w);
        pa[4] = f2b(a1.x); pa[5] = f2b(a1.y); pa[6] = f2b(a1.z); pa[7] = f2b(a1.w);
        *(u16x8*)&Zt[s * 8] = pz;
        *(u16x8*)&At[s * 8] = pa;
    }

    // ---- W fragments direct global->reg (gate_w and out_w, 32-col slice) ----
    bf16x8f gw[2][4], ow[2][4];
    #pragma unroll
    for (int fm = 0; fm < 2; fm++) {
        const int gcol = w * 32 + fm * 16 + lm;
        #pragma unroll
        for (int kk = 0; kk < 4; kk++) {
            const int kb = kk * 32 + lq * 8;
            #pragma unroll
            for (int j = 0; j < 8; j++) {
                gw[fm][kk][j] = (short)f2b(gate_w[(size_t)(kb + j) * CZ + gcol]);
                ow[fm][kk][j] = (short)f2b(out_w [(size_t)(kb + j) * CZ + gcol]);
            }
        }
    }

    __syncthreads();

    // ---- MFMA main: 4 k-steps x 2 col-frags x 4 row-frags x 2 GEMMs ----
    f32x4 acc1[2][4], acc2[2][4];
    #pragma unroll
    for (int fm = 0; fm < 2; fm++)
        #pragma unroll
        for (int fn = 0; fn < 4; fn++) {
            acc1[fm][fn] = (f32x4){0.0f, 0.0f, 0.0f, 0.0f};
            acc2[fm][fn] = (f32x4){0.0f, 0.0f, 0.0f, 0.0f};
        }

    #pragma unroll
    for (int kk = 0; kk < 4; kk++) {
        bf16x8f bz[4], ba[4];
        #pragma unroll
        for (int fn = 0; fn < 4; fn++) {
            const int r = fn * 16 + lm;
            const int ch = (kk * 4 + lq) ^ (r & 7);     // swizzled chunk index
            bz[fn] = *(const bf16x8f*)&Zt[(r * 16 + ch) * 8];
            ba[fn] = *(const bf16x8f*)&At[(r * 16 + ch) * 8];
        }
        #pragma unroll
        for (int fm = 0; fm < 2; fm++)
            #pragma unroll
            for (int fn = 0; fn < 4; fn++) {
                acc1[fm][fn] = __builtin_amdgcn_mfma_f32_16x16x32_bf16(gw[fm][kk], bz[fn],
                                                                       acc1[fm][fn], 0, 0, 0);
                acc2[fm][fn] = __builtin_amdgcn_mfma_f32_16x16x32_bf16(ow[fm][kk], ba[fn],
                                                                       acc2[fm][fn], 0, 0, 0);
            }
    }

    // ---- epilogue: sigmoid-gate + residual, float4 in-place store ----
    #pragma unroll
    for (int fm = 0; fm < 2; fm++) {
        const int gc = w * 32 + fm * 16 + lq * 4;       // out-col of reg 0
        const float4 gb4 = *(const float4*)(gate_b + gc);
        const float4 ob4 = *(const float4*)(out_b + gc);
        #pragma unroll
        for (int fn = 0; fn < 4; fn++) {
            const int grow = row0 + fn * 16 + lm;
            const size_t idx = (size_t)grow * CZ + gc;
            const float4 z4 = *(const float4*)(z + idx);
            float4 o;
            o.x = z4.x + (1.0f / (1.0f + __expf(-(acc1[fm][fn][0] + gb4.x)))) * (acc2[fm][fn][0] + ob4.x);
            o.y = z4.y + (1.0f / (1.0f + __expf(-(acc1[fm][fn][1] + gb4.y)))) * (acc2[fm][fn][1] + ob4.y);
            o.z = z4.z + (1.0f / (1.0f + __expf(-(acc1[fm][fn][2] + gb4.z)))) * (acc2[fm][fn][2] + ob4.z);
            o.w = z4.w + (1.0f / (1.0f + __expf(-(acc1[fm][fn][3] + gb4.w)))) * (acc2[fm][fn][3] + ob4.w);
            *(float4*)(out + idx) = o;
        }
    }
}

// ---------------------------------------------------------------------------
extern "C" void kernel_launch(void* const* d_in, const int* in_sizes, int n_in,
                              void* d_out, int out_size, void* d_ws, size_t ws_size,
                              hipStream_t stream) {
    const float* z      = (const float*)d_in[0];
    const float* ln_w   = (const float*)d_in[1];
    const float* ln_b   = (const float*)d_in[2];
    const float* qkv_w  = (const float*)d_in[3];
    const float* qkv_b  = (const float*)d_in[4];
    const float* out_w  = (const float*)d_in[5];
    const float* out_b  = (const float*)d_in[6];
    const float* gate_w = (const float*)d_in[7];
    const float* gate_b = (const float*)d_in[8];
    float* out = (float*)d_out;

    // Workspace: mu + rstd (f32) + qkv_t (bf16) ~= 114 MiB
    float* ws = (float*)d_ws;
    float* mu_buf   = ws;
    float* rstd_buf = ws + MROWS;
    unsigned short* qkv_t = (unsigned short*)(ws + 2 * MROWS);

    ln_stats_kernel<<<MROWS / 4, 256, 0, stream>>>(z, mu_buf, rstd_buf);
    qkv_gemm_mfma_kernel<<<6912, 256, 0, stream>>>(z, mu_buf, rstd_buf,
                                                   ln_w, ln_b, qkv_w, qkv_b, qkv_t);
    attn_mfma_kernel<<<NN * NH, 256, 0, stream>>>(qkv_t, out);
    final_mfma_kernel<<<MROWS / 64, 256, 0, stream>>>(z, mu_buf, rstd_buf, ln_w, ln_b,
                                                      gate_w, gate_b, out_w, out_b, out);
}

// Round 7
// 368.514 us; speedup vs baseline: 1.1180x; 1.0615x over previous
//
#include <hip/hip_runtime.h>
#include <hip/hip_bf16.h>

// Problem constants
#define NN 384            // sequence dim
#define CZ 128            // channels
#define NH 4              // heads
#define HD 32             // head dim
#define MROWS (NN*NN)     // 147456 GEMM rows

typedef __hip_bfloat16 bf16;
typedef short bf16x8f __attribute__((ext_vector_type(8)));          // MFMA A/B operand (8 bf16)
typedef float f32x4 __attribute__((ext_vector_type(4)));            // MFMA C/D operand
typedef unsigned short u16x8 __attribute__((ext_vector_type(8)));   // staging store type
typedef unsigned int uint4v __attribute__((ext_vector_type(4)));

// bf16 <-> f32 helpers (bit-level, RNE)
__device__ __forceinline__ float b2f(unsigned short u) {
    return __uint_as_float(((unsigned)u) << 16);
}
__device__ __forceinline__ unsigned short f2b(float f) {
    unsigned u = __float_as_uint(f);
    return (unsigned short)((u + 0x7FFFu + ((u >> 16) & 1u)) >> 16);
}
// packed 2xbf16 from 2 floats (RNE), single instruction
__device__ __forceinline__ unsigned cvt_pk_bf16(float lo, float hi) {
    unsigned r;
    asm("v_cvt_pk_bf16_f32 %0, %1, %2" : "=v"(r) : "v"(lo), "v"(hi));
    return r;
}
// raw v_exp_f32 = exp2
__device__ __forceinline__ float fexp2(float x) {
    float r;
    asm("v_exp_f32 %0, %1" : "=v"(r) : "v"(x));
    return r;
}

// ---------------------------------------------------------------------------
// Weight prep (runs once, ~330 KB of reads): transpose + bf16-convert
//   Wt[0   ..383][k] = qkv_w [k][col]      (col 0..383)
//   Wt[384 ..511][k] = gate_w[k][col-384]
//   Wt[512 ..639][k] = out_w [k][col-512]
// A-fragments in the GEMMs then load as single 16-B vectors (was 64 scalar
// f32 loads + 64 f2b chains per thread — the measured instruction bloat).
// ---------------------------------------------------------------------------
__global__ __launch_bounds__(128) void prep_w_kernel(const float* __restrict__ qkv_w,
                                                     const float* __restrict__ gate_w,
                                                     const float* __restrict__ out_w,
                                                     unsigned short* __restrict__ Wt) {
    const int cid = blockIdx.x;      // 0..639
    const int k   = threadIdx.x;     // 0..127
    float v;
    if (cid < 384)      v = qkv_w [(size_t)k * (3 * CZ) + cid];
    else if (cid < 512) v = gate_w[(size_t)k * CZ + (cid - 384)];
    else                v = out_w [(size_t)k * CZ + (cid - 512)];
    Wt[(size_t)cid * CZ + k] = f2b(v);
}

// ---------------------------------------------------------------------------
// LayerNorm apply: one wave per row; writes mu/rstd (for final_mfma) AND the
// bf16 LN(z) row (for qkv staging) into the first 37.7 MB of the out buffer
// (dead by the time attn overwrites out — stream order).  Doing LN once here
// is cheaper than re-deriving it per GEMM tile (round-4 lesson: the shfl
// chain must NOT sit on the GEMM staging critical path).
// ---------------------------------------------------------------------------
__global__ __launch_bounds__(256) void ln_apply_kernel(const float* __restrict__ z,
                                                       const float* __restrict__ lnw,
                                                       const float* __restrict__ lnb,
                                                       float* __restrict__ mu,
                                                       float* __restrict__ rstd,
                                                       unsigned short* __restrict__ lnz) {
    const int wave = threadIdx.x >> 6;
    const int lane = threadIdx.x & 63;
    const int r = blockIdx.x * 4 + wave;
    const float* zr = z + (size_t)r * CZ;
    const float x0 = zr[lane], x1 = zr[lane + 64];
    float sum = x0 + x1;
    float sq  = x0 * x0 + x1 * x1;
    #pragma unroll
    for (int o = 32; o > 0; o >>= 1) {
        sum += __shfl_xor(sum, o, 64);
        sq  += __shfl_xor(sq,  o, 64);
    }
    const float m  = sum * (1.0f / CZ);
    const float rs = rsqrtf(sq * (1.0f / CZ) - m * m + 1e-5f);
    if (lane == 0) {
        mu[r]   = m;
        rstd[r] = rs;
    }
    const float w0 = lnw[lane], w1 = lnw[lane + 64];
    const float b0 = lnb[lane], b1 = lnb[lane + 64];
    lnz[(size_t)r * CZ + lane]      = f2b((x0 - m) * rs * w0 + b0);
    lnz[(size_t)r * CZ + lane + 64] = f2b((x1 - m) * rs * w1 + b1);
}

// ---------------------------------------------------------------------------
// qkv GEMM on MFMA: qkv = LNz @ qkv_w + qkv_b, scattered as bf16 into
// qkv_t[t][h][n][i][d].  LNz read as bf16 (precomputed) -> staging is a pure
// 16-B copy with the XOR swizzle folded into the SOURCE address; W frags are
// single 16-B loads from Wt.  Operands SWAPPED: mfma(A = W-cols frag,
// B = LNz-rows frag) so the 4 acc regs are 4 consecutive out-cols.
// XCD-CHUNKED grid (1D): xcd = bid&7 owns 144 consecutive row-panels, col
// fastest within -> the 6 col-blocks sharing a row-panel hit the same XCD L2
// (verified: FETCH 222 MB -> 38.5 MB in round 6).  LDS: 32 KB.
// ---------------------------------------------------------------------------
__global__ __launch_bounds__(256) void qkv_gemm_mfma_kernel(const unsigned short* __restrict__ lnz,
                                                            const unsigned short* __restrict__ Wt,
                                                            const float* __restrict__ bias,
                                                            unsigned short* __restrict__ qkv_t) {
    __shared__ unsigned short Zt[128 * 128];   // 32 KB: slot16 (row, c') holds k-chunk c'^(row&7)

    const int tid = threadIdx.x;
    const int w = tid >> 6;
    const int l = tid & 63;
    // XCD-chunked decomposition: 6912 = 8 XCDs x 144 row-panels x 6 col-blocks
    const int bid = blockIdx.x;
    const int xcd = bid & 7;
    const int idx = bid >> 3;            // 0..863
    const int yt  = idx / 6;             // 0..143
    const int x   = idx - yt * 6;        // 0..5
    const int col0 = x * 64;
    const int row0 = (xcd * 144 + yt) * 128;
    const int wcol = w & 1;
    const int wrow = w >> 1;
    const int lm = l & 15;
    const int lq = l >> 4;

    // ---- stage LNz tile (bf16, swizzled source -> linear LDS slots) ----
    #pragma unroll
    for (int it = 0; it < 8; it++) {
        const int s = it * 256 + tid;          // 2048 16B slots
        const int r = s >> 4;
        const int cc = (s & 15) ^ (r & 7);     // swizzle on SOURCE chunk
        *(u16x8*)&Zt[s * 8] =
            *(const u16x8*)(lnz + (size_t)(row0 + r) * CZ + cc * 8);
    }

    // ---- W fragments: single 16-B loads from pre-transposed bf16 Wt ----
    bf16x8f a[2][4];
    #pragma unroll
    for (int fm = 0; fm < 2; fm++) {
        const int gcol = col0 + wcol * 32 + fm * 16 + lm;
        #pragma unroll
        for (int kk = 0; kk < 4; kk++)
            a[fm][kk] = *(const bf16x8f*)(Wt + (size_t)gcol * CZ + kk * 32 + lq * 8);
    }

    __syncthreads();

    // ---- MFMA main: 4 k-steps x (2 col-frags x 4 row-frags) = 32 MFMA/wave
    f32x4 acc[2][4];
    #pragma unroll
    for (int fm = 0; fm < 2; fm++)
        #pragma unroll
        for (int fn = 0; fn < 4; fn++)
            acc[fm][fn] = (f32x4){0.0f, 0.0f, 0.0f, 0.0f};

    #pragma unroll
    for (int kk = 0; kk < 4; kk++) {
        bf16x8f bf[4];
        #pragma unroll
        for (int fn = 0; fn < 4; fn++) {
            const int r = wrow * 64 + fn * 16 + lm;
            const int ch = (kk * 4 + lq) ^ (r & 7);     // swizzled chunk index
            bf[fn] = *(const bf16x8f*)&Zt[(r * 16 + ch) * 8];
        }
        #pragma unroll
        for (int fm = 0; fm < 2; fm++)
            #pragma unroll
            for (int fn = 0; fn < 4; fn++)
                acc[fm][fn] = __builtin_amdgcn_mfma_f32_16x16x32_bf16(a[fm][kk], bf[fn],
                                                                      acc[fm][fn], 0, 0, 0);
    }

    // ---- epilogue: bias + pack + scatter (4 consecutive d per ushort4) ----
    #pragma unroll
    for (int fm = 0; fm < 2; fm++) {
        const int gc = col0 + wcol * 32 + fm * 16 + lq * 4;   // out-col of reg 0
        const float4 b4 = *(const float4*)(bias + gc);
        const int t  = gc >> 7;
        const int hh = (gc & 127) >> 5;
        const int d0 = gc & 31;
        const size_t colbase = (size_t)((t * NH + hh) * NN) * (NN * HD) + d0;
        #pragma unroll
        for (int fn = 0; fn < 4; fn++) {
            const int grow = row0 + wrow * 64 + fn * 16 + lm;  // = i*NN + n
            const int i  = grow / NN;
            const int n0 = grow - i * NN;
            const size_t idx2 = colbase + (size_t)n0 * (NN * HD) + (size_t)i * HD;
            ushort4 pk;
            pk.x = f2b(acc[fm][fn][0] + b4.x);
            pk.y = f2b(acc[fm][fn][1] + b4.y);
            pk.z = f2b(acc[fm][fn][2] + b4.z);
            pk.w = f2b(acc[fm][fn][3] + b4.w);
            *(ushort4*)(qkv_t + idx2) = pk;
        }
    }
}

// ---------------------------------------------------------------------------
// MFMA attention per (n,h), single pass, in-register P transpose, SOFTWARE-
// PIPELINED: one barrier per j-tile.  Double-buffered Vf/sred; PV(cl-1) runs
// in the same barrier-free region as V'(cl) staging and the next tile's
// S/exp VALU.  Q frags direct from global; cl-loop fully unrolled (static
// paw double-buffer).  exp via raw v_exp_f32 with scale*log2e folded.
// LDS: Kf 24K + Vf 4K + sred 1K = 29 KB.
// ---------------------------------------------------------------------------
__global__ __launch_bounds__(256) void attn_mfma_kernel(const unsigned short* __restrict__ qkv_t,
                                                        float* __restrict__ attn_out) {
    __shared__ unsigned short Kf[24 * 512];    // frag-order: tile*512 + lane*8
    __shared__ unsigned short Vf[2][1024];     // double-buffered B-frags for j-tile
    __shared__ float sred[2][4][32];           // double-buffered per-wave colsum partials

    const int b = blockIdx.x;
    const int n = b >> 2;
    const int h = b & 3;
    const int tid = threadIdx.x;
    const int w = tid >> 6;        // wave 0..3
    const int l = tid & 63;        // lane
    const int q = l >> 4;          // quad 0..3
    const int m = l & 15;          // low lane bits
    const size_t base_q = (size_t)((0 * NH + h) * NN + n) * (NN * HD);
    const size_t base_k = (size_t)((1 * NH + h) * NN + n) * (NN * HD);
    const size_t base_v = (size_t)((2 * NH + h) * NN + n) * (NN * HD);
    const float SC2 = 0.17677669529663687f * 1.4426950408889634f;  // scale*log2(e)
    const f32x4 zero = {0.0f, 0.0f, 0.0f, 0.0f};

    // ---- Stage K into fragment-order LDS (1536 16B slots) ----
    #pragma unroll
    for (int it = 0; it < 6; it++) {
        const int slot = tid + it * 256;
        const int t  = slot >> 6;
        const int l2 = slot & 63;
        const int row = t * 16 + (l2 & 15);
        const int off8 = (l2 >> 4) * 8;
        *(u16x8*)(Kf + slot * 8) =
            *(const u16x8*)(qkv_t + base_k + (size_t)row * HD + off8);
    }
    // ---- Q fragments DIRECT from global (layout == fragment layout) ----
    bf16x8f qreg[6];
    #pragma unroll
    for (int tt = 0; tt < 6; tt++) {
        const int row = (w + 4 * tt) * 16 + m;
        qreg[tt] = *(const bf16x8f*)(qkv_t + base_q + (size_t)row * HD + q * 8);
    }
    __syncthreads();

    f32x4 oacc[6][2];
    #pragma unroll
    for (int tt = 0; tt < 6; tt++) {
        oacc[tt][0] = zero;
        oacc[tt][1] = zero;
    }

    unsigned pawA[6][4], pawB[6][4];     // double-buffered PV A-frag words
    const int jj  = tid >> 3;            // 0..31 local j (V staging role)
    const int d0v = (tid & 7) * 4;       // 0..28
    const int slotbase = (d0v >> 4) * 64 + (jj >> 3) * 16 + (d0v & 15);
    const int e = jj & 7;

    #pragma unroll
    for (int cl = 0; cl < 12; cl++) {
        const int buf = cl & 1;          // folds: loop fully unrolled
        const bf16x8f ka0 = *(const bf16x8f*)&Kf[(cl * 2 + 0) * 512 + l * 8];
        const bf16x8f ka1 = *(const bf16x8f*)&Kf[(cl * 2 + 1) * 512 + l * 8];
        // prefetch this tile's V rows (hides global latency under S compute)
        const ushort4 v4 = *(const ushort4*)(qkv_t + base_v +
                                             (size_t)(cl * 32 + jj) * HD + d0v);

        float sacc[8];
        #pragma unroll
        for (int k = 0; k < 8; k++) sacc[k] = 0.0f;

        #pragma unroll
        for (int tt = 0; tt < 6; tt++) {
            // S^T tiles: rows j (quad*4+reg), cols i (m); computed ONCE
            const f32x4 sT0 = __builtin_amdgcn_mfma_f32_16x16x32_bf16(ka0, qreg[tt], zero, 0, 0, 0);
            const f32x4 sT1 = __builtin_amdgcn_mfma_f32_16x16x32_bf16(ka1, qreg[tt], zero, 0, 0, 0);
            float p[8];
            p[0] = fexp2(sT0[0] * SC2);
            p[1] = fexp2(sT0[1] * SC2);
            p[2] = fexp2(sT0[2] * SC2);
            p[3] = fexp2(sT0[3] * SC2);
            p[4] = fexp2(sT1[0] * SC2);
            p[5] = fexp2(sT1[1] * SC2);
            p[6] = fexp2(sT1[2] * SC2);
            p[7] = fexp2(sT1[3] * SC2);
            #pragma unroll
            for (int k = 0; k < 8; k++) sacc[k] += p[k];
            // pack: c[2s+u] holds word W = 8s+4h+2g+u (h,g = lane bits 5,4)
            unsigned c0 = cvt_pk_bf16(p[0], p[1]);
            unsigned c1 = cvt_pk_bf16(p[2], p[3]);
            unsigned c2 = cvt_pk_bf16(p[4], p[5]);
            unsigned c3 = cvt_pk_bf16(p[6], p[7]);
            // in-register transpose (h,g,s) -> (s,h,g):
            asm("v_permlane32_swap_b32 %0, %1" : "+v"(c0), "+v"(c2));
            asm("v_permlane32_swap_b32 %0, %1" : "+v"(c1), "+v"(c3));
            asm("v_permlane16_swap_b32 %0, %1" : "+v"(c0), "+v"(c2));
            asm("v_permlane16_swap_b32 %0, %1" : "+v"(c1), "+v"(c3));
            if (buf == 0) {
                pawA[tt][0] = c0; pawA[tt][1] = c1; pawA[tt][2] = c2; pawA[tt][3] = c3;
            } else {
                pawB[tt][0] = c0; pawB[tt][1] = c1; pawB[tt][2] = c2; pawB[tt][3] = c3;
            }
        }

        // ---- column-sum partials: reduce over i-lanes (m), write sred ----
        #pragma unroll
        for (int k = 0; k < 8; k++) {
            float v = sacc[k];
            v += __shfl_xor(v, 1, 64);
            v += __shfl_xor(v, 2, 64);
            v += __shfl_xor(v, 4, 64);
            v += __shfl_xor(v, 8, 64);
            if (m == 0) sred[buf][w][q * 4 + (k & 3) + (k >> 2) * 16] = v;
        }
        __syncthreads();   // the ONLY barrier per j-tile

        // ---- stage V'[j] = V[j]/s_j into Vf[buf] (prefetched v4) ----
        {
            const float inv = 1.0f / (sred[buf][0][jj] + sred[buf][1][jj] +
                                      sred[buf][2][jj] + sred[buf][3][jj]);
            Vf[buf][(slotbase + 0) * 8 + e] = f2b(b2f(v4.x) * inv);
            Vf[buf][(slotbase + 1) * 8 + e] = f2b(b2f(v4.y) * inv);
            Vf[buf][(slotbase + 2) * 8 + e] = f2b(b2f(v4.z) * inv);
            Vf[buf][(slotbase + 3) * 8 + e] = f2b(b2f(v4.w) * inv);
        }

        // ---- PV(cl-1) from Vf[buf^1] + paw(prev): overlaps staging and the
        //      next tile's S/exp VALU (no barrier in between) ----
        if (cl > 0) {
            const bf16x8f vb0 = *(const bf16x8f*)&Vf[buf ^ 1][(0 * 64 + l) * 8];
            const bf16x8f vb1 = *(const bf16x8f*)&Vf[buf ^ 1][(1 * 64 + l) * 8];
            #pragma unroll
            for (int tt = 0; tt < 6; tt++) {
                uint4v u;
                if (buf == 1) { u = (uint4v){pawA[tt][0], pawA[tt][1], pawA[tt][2], pawA[tt][3]}; }
                else          { u = (uint4v){pawB[tt][0], pawB[tt][1], pawB[tt][2], pawB[tt][3]}; }
                const bf16x8f pa = __builtin_bit_cast(bf16x8f, u);
                oacc[tt][0] = __builtin_amdgcn_mfma_f32_16x16x32_bf16(pa, vb0, oacc[tt][0], 0, 0, 0);
                oacc[tt][1] = __builtin_amdgcn_mfma_f32_16x16x32_bf16(pa, vb1, oacc[tt][1], 0, 0, 0);
            }
        }
    }

    // ---- drain: PV(11) from Vf[1] + pawB ----
    __syncthreads();
    {
        const bf16x8f vb0 = *(const bf16x8f*)&Vf[1][(0 * 64 + l) * 8];
        const bf16x8f vb1 = *(const bf16x8f*)&Vf[1][(1 * 64 + l) * 8];
        #pragma unroll
        for (int tt = 0; tt < 6; tt++) {
            const uint4v u = {pawB[tt][0], pawB[tt][1], pawB[tt][2], pawB[tt][3]};
            const bf16x8f pa = __builtin_bit_cast(bf16x8f, u);
            oacc[tt][0] = __builtin_amdgcn_mfma_f32_16x16x32_bf16(pa, vb0, oacc[tt][0], 0, 0, 0);
            oacc[tt][1] = __builtin_amdgcn_mfma_f32_16x16x32_bf16(pa, vb1, oacc[tt][1], 0, 0, 0);
        }
    }

    // ---- Store O: rows i = it*16 + q*4 + r, col d = dt*16 + m ----
    #pragma unroll
    for (int tt = 0; tt < 6; tt++) {
        const int it = w + 4 * tt;
        #pragma unroll
        for (int dt = 0; dt < 2; dt++) {
            #pragma unroll
            for (int r = 0; r < 4; r++) {
                const int i = it * 16 + q * 4 + r;
                attn_out[((size_t)i * NN + n) * CZ + h * HD + dt * 16 + m] = oacc[tt][dt][r];
            }
        }
    }
}

// ---------------------------------------------------------------------------
// Final dual GEMM on MFMA (bf16 inputs, f32 accumulate), in place on out:
//   out = z + sigmoid(LN(z)@gate_w+gate_b) * (attn@out_w + out_b)
// Tile: 64 rows x 128 cols (full N), K = 128 in one shot; 4 waves each own a
// 32-col slice.  Both row operands staged as bf16 into XOR-swizzled LDS.
// LN from precomputed mu/rstd; W frags from pre-transposed bf16 Gt/Ot.
// ---------------------------------------------------------------------------
__global__ __launch_bounds__(256) void final_mfma_kernel(const float* __restrict__ z,
                                                         const float* __restrict__ mu,
                                                         const float* __restrict__ rstd,
                                                         const float* __restrict__ lnw,
                                                         const float* __restrict__ lnb,
                                                         const unsigned short* __restrict__ Gt,
                                                         const float* __restrict__ gate_b,
                                                         const unsigned short* __restrict__ Ot,
                                                         const float* __restrict__ out_b,
                                                         float* out) {
    __shared__ unsigned short Zt[64 * 128];   // LN(z) bf16, swizzled (16 KB)
    __shared__ unsigned short At[64 * 128];   // attn  bf16, swizzled (16 KB)

    const int tid = threadIdx.x;
    const int w = tid >> 6;        // wave = col slice 0..3 (32 cols each)
    const int l = tid & 63;
    const int lm = l & 15;
    const int lq = l >> 4;
    const int row0 = blockIdx.x * 64;

    // ---- stage LN(z) and attn tiles into swizzled LDS as bf16 ----
    #pragma unroll
    for (int it = 0; it < 4; it++) {
        const int s = it * 256 + tid;          // 1024 16B slots
        const int r = s >> 4;                  // 0..63
        const int c = (s & 15) ^ (r & 7);      // inverse swizzle on source chunk
        const int k0 = c * 8;
        const int grow = row0 + r;
        const float m  = mu[grow];
        const float rs = rstd[grow];
        const size_t gi = (size_t)grow * CZ + k0;
        const float4 z0 = *(const float4*)(z + gi);
        const float4 z1 = *(const float4*)(z + gi + 4);
        const float4 a0 = *(const float4*)(out + gi);
        const float4 a1 = *(const float4*)(out + gi + 4);
        const float4 w0 = *(const float4*)(lnw + k0);
        const float4 w1 = *(const float4*)(lnw + k0 + 4);
        const float4 b0 = *(const float4*)(lnb + k0);
        const float4 b1 = *(const float4*)(lnb + k0 + 4);
        u16x8 pz, pa;
        pz[0] = f2b((z0.x - m) * rs * w0.x + b0.x);
        pz[1] = f2b((z0.y - m) * rs * w0.y + b0.y);
        pz[2] = f2b((z0.z - m) * rs * w0.z + b0.z);
        pz[3] = f2b((z0.w - m) * rs * w0.w + b0.w);
        pz[4] = f2b((z1.x - m) * rs * w1.x + b1.x);
        pz[5] = f2b((z1.y - m) * rs * w1.y + b1.y);
        pz[6] = f2b((z1.z - m) * rs * w1.z + b1.z);
        pz[7] = f2b((z1.w - m) * rs * w1.w + b1.w);
        pa[0] = f2b(a0.x); pa[1] = f2b(a0.y); pa[2] = f2b(a0.z); pa[3] = f2b(a0.w);
        pa[4] = f2b(a1.x); pa[5] = f2b(a1.y); pa[6] = f2b(a1.z); pa[7] = f2b(a1.w);
        *(u16x8*)&Zt[s * 8] = pz;
        *(u16x8*)&At[s * 8] = pa;
    }

    // ---- W fragments: single 16-B loads from pre-transposed bf16 Gt/Ot ----
    bf16x8f gw[2][4], ow[2][4];
    #pragma unroll
    for (int fm = 0; fm < 2; fm++) {
        const int gcol = w * 32 + fm * 16 + lm;
        #pragma unroll
        for (int kk = 0; kk < 4; kk++) {
            const int kb = kk * 32 + lq * 8;
            gw[fm][kk] = *(const bf16x8f*)(Gt + (size_t)gcol * CZ + kb);
            ow[fm][kk] = *(const bf16x8f*)(Ot + (size_t)gcol * CZ + kb);
        }
    }

    __syncthreads();

    // ---- MFMA main: 4 k-steps x 2 col-frags x 4 row-frags x 2 GEMMs ----
    f32x4 acc1[2][4], acc2[2][4];
    #pragma unroll
    for (int fm = 0; fm < 2; fm++)
        #pragma unroll
        for (int fn = 0; fn < 4; fn++) {
            acc1[fm][fn] = (f32x4){0.0f, 0.0f, 0.0f, 0.0f};
            acc2[fm][fn] = (f32x4){0.0f, 0.0f, 0.0f, 0.0f};
        }

    #pragma unroll
    for (int kk = 0; kk < 4; kk++) {
        bf16x8f bz[4], ba[4];
        #pragma unroll
        for (int fn = 0; fn < 4; fn++) {
            const int r = fn * 16 + lm;
            const int ch = (kk * 4 + lq) ^ (r & 7);     // swizzled chunk index
            bz[fn] = *(const bf16x8f*)&Zt[(r * 16 + ch) * 8];
            ba[fn] = *(const bf16x8f*)&At[(r * 16 + ch) * 8];
        }
        #pragma unroll
        for (int fm = 0; fm < 2; fm++)
            #pragma unroll
            for (int fn = 0; fn < 4; fn++) {
                acc1[fm][fn] = __builtin_amdgcn_mfma_f32_16x16x32_bf16(gw[fm][kk], bz[fn],
                                                                       acc1[fm][fn], 0, 0, 0);
                acc2[fm][fn] = __builtin_amdgcn_mfma_f32_16x16x32_bf16(ow[fm][kk], ba[fn],
                                                                       acc2[fm][fn], 0, 0, 0);
            }
    }

    // ---- epilogue: sigmoid-gate + residual, float4 in-place store ----
    #pragma unroll
    for (int fm = 0; fm < 2; fm++) {
        const int gc = w * 32 + fm * 16 + lq * 4;       // out-col of reg 0
        const float4 gb4 = *(const float4*)(gate_b + gc);
        const float4 ob4 = *(const float4*)(out_b + gc);
        #pragma unroll
        for (int fn = 0; fn < 4; fn++) {
            const int grow = row0 + fn * 16 + lm;
            const size_t idx = (size_t)grow * CZ + gc;
            const float4 z4 = *(const float4*)(z + idx);
            float4 o;
            o.x = z4.x + (1.0f / (1.0f + __expf(-(acc1[fm][fn][0] + gb4.x)))) * (acc2[fm][fn][0] + ob4.x);
            o.y = z4.y + (1.0f / (1.0f + __expf(-(acc1[fm][fn][1] + gb4.y)))) * (acc2[fm][fn][1] + ob4.y);
            o.z = z4.z + (1.0f / (1.0f + __expf(-(acc1[fm][fn][2] + gb4.z)))) * (acc2[fm][fn][2] + ob4.z);
            o.w = z4.w + (1.0f / (1.0f + __expf(-(acc1[fm][fn][3] + gb4.w)))) * (acc2[fm][fn][3] + ob4.w);
            *(float4*)(out + idx) = o;
        }
    }
}

// ---------------------------------------------------------------------------
extern "C" void kernel_launch(void* const* d_in, const int* in_sizes, int n_in,
                              void* d_out, int out_size, void* d_ws, size_t ws_size,
                              hipStream_t stream) {
    const float* z      = (const float*)d_in[0];
    const float* ln_w   = (const float*)d_in[1];
    const float* ln_b   = (const float*)d_in[2];
    const float* qkv_w  = (const float*)d_in[3];
    const float* qkv_b  = (const float*)d_in[4];
    const float* out_w  = (const float*)d_in[5];
    const float* out_b  = (const float*)d_in[6];
    const float* gate_w = (const float*)d_in[7];
    const float* gate_b = (const float*)d_in[8];
    float* out = (float*)d_out;

    // Workspace: mu + rstd (f32) + Wt (bf16, 160 KB) + qkv_t (bf16) ~= 114.6 MiB
    float* ws = (float*)d_ws;
    float* mu_buf   = ws;
    float* rstd_buf = ws + MROWS;
    unsigned short* Wt    = (unsigned short*)(ws + 2 * MROWS);
    unsigned short* Gt    = Wt + 384 * CZ;
    unsigned short* Ot    = Wt + 512 * CZ;
    unsigned short* qkv_t = Wt + 640 * CZ;
    // LN(z) bf16 lives in the first 37.7 MB of out: dead before attn writes.
    unsigned short* lnz = (unsigned short*)out;

    prep_w_kernel<<<640, 128, 0, stream>>>(qkv_w, gate_w, out_w, Wt);
    ln_apply_kernel<<<MROWS / 4, 256, 0, stream>>>(z, ln_w, ln_b, mu_buf, rstd_buf, lnz);
    qkv_gemm_mfma_kernel<<<6912, 256, 0, stream>>>(lnz, Wt, qkv_b, qkv_t);
    attn_mfma_kernel<<<NN * NH, 256, 0, stream>>>(qkv_t, out);
    final_mfma_kernel<<<MROWS / 64, 256, 0, stream>>>(z, mu_buf, rstd_buf, ln_w, ln_b,
                                                      Gt, gate_b, Ot, out_b, out);
}